// Round 9
// baseline (37.568 us; speedup 1.0000x reference)
//
#include <hip/hip_runtime.h>
#include <stdint.h>

#define NB    4
#define NL0   2048
#define NL1   2048
#define NC    64
#define KMAX  128
#define CAP   192
#define NSLOT 3
#define NG1   9
#define NBINS 729
#define FLOWN (NB*NL0*3)
#define QPB   8
#define TPB   512
#define NCELL1  6
#define NCELLS  216        // 6^3
#define CSTRIDE 217
// ws layout: srec float4[NB*NL1] @ 0 (128 KB); cstart u32[NB*CSTRIDE] @ 131072

// ---- prep: per-batch counting sort of points into 6^3 cells ----
__global__ __launch_bounds__(256) void prep_kernel(
    const float* __restrict__ pos1, const void* __restrict__ padraw,
    float4* __restrict__ srec, uint32_t* __restrict__ cstart)
{
  __shared__ uint32_t s_hist[256];
  __shared__ uint32_t s_off[256];
  __shared__ uint8_t  s_cell[NL1];
  __shared__ uint8_t  s_padc[NL1];
  const int t = threadIdx.x, b = blockIdx.x;

  // pad dtype detection (whole array, same predicate as passing rounds)
  int ok4 = 1;
  const uint32_t* pw = (const uint32_t*)padraw;
  for (int i = t; i < (NB*NL1)/4; i += 256) {
    const uint32_t v = pw[i];
    ok4 &= (int)((v <= 1u) | (v == 0x3F800000u));
  }
  const int wide = __syncthreads_and(ok4);

  s_hist[t] = 0;
  __syncthreads();

  const float* pb = pos1 + (size_t)b*NL1*3;
  for (int j = t; j < NL1; j += 256) {
    uint8_t pv;
    if (wide) pv = (pw[b*NL1 + j] != 0u);
    else      pv = (((const uint8_t*)padraw)[b*NL1 + j] != 0);
    s_padc[j] = pv;
    const float x = pb[j*3+0], y = pb[j*3+1], z = pb[j*3+2];
    int cx = (int)(x*5.5f); cx = cx<0?0:(cx>5?5:cx);   // cell width 0.1818 > R=0.18
    int cy = (int)(y*5.5f); cy = cy<0?0:(cy>5?5:cy);
    int cz = (int)(z*5.5f); cz = cz<0?0:(cz>5?5:cz);
    const int c = (cx*NCELL1 + cy)*NCELL1 + cz;
    s_cell[j] = (uint8_t)c;
    atomicAdd(&s_hist[c], 1u);
  }
  __syncthreads();
  s_off[t] = s_hist[t];                 // save counts
  __syncthreads();
  for (int d = 1; d < 256; d <<= 1) {   // Hillis-Steele inclusive scan
    const uint32_t add = (t >= d) ? s_hist[t-d] : 0u;
    __syncthreads();
    s_hist[t] += add;
    __syncthreads();
  }
  const uint32_t startv = s_hist[t] - s_off[t];   // exclusive
  __syncthreads();
  s_off[t] = startv;
  if (t < NCELLS) cstart[b*CSTRIDE + t] = startv;
  if (t == 255)  cstart[b*CSTRIDE + NCELLS] = s_hist[255];
  __syncthreads();

  for (int j = t; j < NL1; j += 256) {
    const int c = (int)s_cell[j];
    const uint32_t dst = atomicAdd(&s_off[c], 1u);
    float4 r;
    r.x = pb[j*3+0]; r.y = pb[j*3+1]; r.z = pb[j*3+2];
    r.w = __int_as_float((j << 1) | (int)s_padc[j]);
    srec[(size_t)b*NL1 + dst] = r;
  }
}

// ---- main ----
__global__ __launch_bounds__(TPB, 8) void fine_match_kernel(
    const float* __restrict__ x0, const float* __restrict__ x1,
    const float* __restrict__ pos0,
    const float4* __restrict__ srec, const uint32_t* __restrict__ cstart,
    float* __restrict__ out)
{
  __shared__ uint32_t       s_cells[CSTRIDE];
  __shared__ float          s_x0[QPB*NC];
  __shared__ float          s_p0[QPB][3];
  __shared__ unsigned short s_jj[QPB][CAP];
  __shared__ float          s_corr[QPB][CAP];

  const int t = threadIdx.x;
  const int bid = blockIdx.x;
  const int b = bid >> 8;                 // 256 blocks per batch
  const int l0base = (bid & 255) * QPB;

  { // zero-fill this block's flow_dist region first
    float4 z4; z4.x = z4.y = z4.z = z4.w = 0.0f;
    float4* bz = (float4*)(out + FLOWN + (size_t)(b*NL0 + l0base)*NBINS);
    for (int i = t; i < QPB*NBINS/4; i += TPB) bz[i] = z4;
  }
  if (t < CSTRIDE) s_cells[t] = cstart[b*CSTRIDE + t];
  s_x0[t] = x0[(size_t)(b*NL0 + l0base)*NC + t];              // TPB == QPB*NC
  if (t < QPB*3) {
    const int q = t/3, c = t - q*3;
    s_p0[q][c] = pos0[(b*NL0 + l0base + q)*3 + c];
  }
  __syncthreads();   // LDS visible + zero-stores drained before any atomics

  const int wv = t >> 6, lane = t & 63;
  const int l0 = l0base + wv;
  const float p0x = s_p0[wv][0], p0y = s_p0[wv][1], p0z = s_p0[wv][2];
  const float4* srb = srec + (size_t)b*NL1;

  // home cell + 9 contiguous z-column ranges (27 cells)
  int hx = (int)(p0x*5.5f); hx = hx<0?0:(hx>5?5:hx);
  int hy = (int)(p0y*5.5f); hy = hy<0?0:(hy>5?5:hy);
  int hz = (int)(p0z*5.5f); hz = hz<0?0:(hz>5?5:hz);
  const int zlo = hz>0 ? hz-1 : 0;
  const int zhi = hz<5 ? hz+1 : 5;

  int preA[9], offA[9];
  int acc = 0;
  #pragma unroll
  for (int r = 0; r < 9; ++r) {
    const int cx = hx + r/3 - 1, cy = hy + (r%3) - 1;
    const bool okc = (cx>=0) & (cx<6) & (cy>=0) & (cy<6);
    const int baseI = okc ? (cx*NCELL1 + cy)*NCELL1 : 0;
    const int sA = (int)s_cells[baseI + zlo];
    const int eA = (int)s_cells[baseI + zhi + 1];
    const int len = okc ? (eA - sA) : 0;
    preA[r] = acc;
    offA[r] = sA - acc;
    acc += len;
  }
  const int T = acc;

  // phase 1: radius test over ~T candidates + wave compaction
  int cnt = 0;
  for (int base0 = 0; base0 < T; base0 += 64) {
    const int slot = base0 + lane;
    int sidx = 0;
    #pragma unroll
    for (int r = 0; r < 9; ++r)           // last true r wins (ranges ascending)
      sidx = (slot >= preA[r]) ? (slot + offA[r]) : sidx;
    const bool in = slot < T;
    if (!in) sidx = 0;
    const float4 rec = srb[sidx];
    const float dx = __fsub_rn(rec.x, p0x);
    const float dy = __fsub_rn(rec.y, p0y);
    const float dz = __fsub_rn(rec.z, p0z);
    const float d2 = __fadd_rn(__fadd_rn(__fmul_rn(dx,dx), __fmul_rn(dy,dy)), __fmul_rn(dz,dz));
    const bool ok = in && (d2 < 0.0324f);            // strict <, matches reference
    const uint64_t m = __ballot(ok);
    if (ok) {
      const int pos = cnt + (int)__popcll(m & ((1ull << lane) - 1ull));
      if (pos < CAP) s_jj[wv][pos] = (unsigned short)sidx;
    }
    cnt += (int)__popcll(m);
  }
  if (cnt > CAP) cnt = CAP;
  // no barrier: s_jj / s_corr are wave-private from here on

  // phase 2: pad filter, rare exact rank-select, correlation
  const bool over = (cnt > KMAX);
  for (int s = 0; s < NSLOT; ++s) {
    if (64*s >= cnt) break;                  // wave-uniform early exit
    const int i = lane + 64*s;
    if (i < cnt) {
      float c = -1e30f;
      const int sidx = (int)s_jj[wv][i];
      const float4 rec = srb[sidx];
      const int bits = __float_as_int(rec.w);
      const int j = bits >> 1;
      bool k = ((bits & 1) == 0);
      if (over && k) {  // rank over ALL in-radius candidates, tie-break by list order
        const float dx = __fsub_rn(rec.x, p0x);
        const float dy = __fsub_rn(rec.y, p0y);
        const float dz = __fsub_rn(rec.z, p0z);
        const float di = __fadd_rn(__fadd_rn(__fmul_rn(dx,dx), __fmul_rn(dy,dy)), __fmul_rn(dz,dz));
        int rank = 0;
        for (int m2 = 0; m2 < cnt; ++m2) {
          const float4 pm = srb[(int)s_jj[wv][m2]];
          const float ex = __fsub_rn(pm.x, p0x);
          const float ey = __fsub_rn(pm.y, p0y);
          const float ez = __fsub_rn(pm.z, p0z);
          const float dm = __fadd_rn(__fadd_rn(__fmul_rn(ex,ex), __fmul_rn(ey,ey)), __fmul_rn(ez,ez));
          rank += (dm < di || (dm == di && m2 < i)) ? 1 : 0;
        }
        if (rank >= KMAX) k = false;
      }
      if (k) {
        const float* xr = x1 + ((size_t)b*NL1 + j)*NC;
        float acc2 = 0.0f;
        #pragma unroll
        for (int cc = 0; cc < NC; cc += 4) {
          const float4 v = *(const float4*)(xr + cc);
          const float4 q = *(const float4*)(&s_x0[wv*NC + cc]);  // broadcast
          acc2 += q.x*v.x + q.y*v.y + q.z*v.z + q.w*v.w;
        }
        c = acc2 * 0.125f;   // / sqrt(64)
      }
      s_corr[wv][i] = c;
    }
  }

  // phase 3: wave softmax stats (max, sum)
  float mx = -1e30f;
  for (int s = 0; s < NSLOT; ++s) {
    if (64*s >= cnt) break;
    const int i = lane + 64*s;
    if (i < cnt) { const float c = s_corr[wv][i]; if (c > mx) mx = c; }
  }
  for (int off = 32; off; off >>= 1) { const float o = __shfl_xor(mx, off); if (o > mx) mx = o; }
  float sum = 0.0f;
  for (int s = 0; s < NSLOT; ++s) {
    if (64*s >= cnt) break;
    const int i = lane + 64*s;
    if (i < cnt) { const float c = s_corr[wv][i]; if (c > -1e30f) sum += expf(c - mx); }
  }
  for (int off = 32; off; off >>= 1) sum += __shfl_xor(sum, off);
  const float inv = (sum > 0.0f) ? (1.0f / sum) : 0.0f;

  // phase 4: flow + voxel scatter (workgroup-scope atomics into local L2)
  float* bins = out + FLOWN + (size_t)((size_t)b*NL0 + l0)*NBINS;
  float fx = 0.0f, fy = 0.0f, fz = 0.0f;
  for (int s = 0; s < NSLOT; ++s) {
    if (64*s >= cnt) break;
    const int i = lane + 64*s;
    if (i < cnt) {
      const float c = s_corr[wv][i];
      if (c > -1e30f) {
        const float pv = expf(c - mx) * inv;     // identical to phase-3 term * inv
        const float4 rec = srb[(int)s_jj[wv][i]];
        const float dx = __fsub_rn(rec.x, p0x);
        const float dy = __fsub_rn(rec.y, p0y);
        const float dz = __fsub_rn(rec.z, p0z);
        fx += pv*dx; fy += pv*dy; fz += pv*dz;
        const float cx = __fdiv_rn(__fadd_rn(dx, 0.16f), 0.04f);
        const float cy = __fdiv_rn(__fadd_rn(dy, 0.16f), 0.04f);
        const float cz = __fdiv_rn(__fadd_rn(dz, 0.16f), 0.04f);
        int vx = (int)rintf(cx); vx = vx < 0 ? 0 : (vx > 8 ? 8 : vx);
        int vy = (int)rintf(cy); vy = vy < 0 ? 0 : (vy > 8 ? 8 : vy);
        int vz = (int)rintf(cz); vz = vz < 0 ? 0 : (vz > 8 ? 8 : vz);
        __hip_atomic_fetch_add(&bins[(vx*NG1 + vy)*NG1 + vz], pv,
                               __ATOMIC_RELAXED, __HIP_MEMORY_SCOPE_WORKGROUP);
      }
    }
  }
  for (int off = 32; off; off >>= 1) {
    fx += __shfl_xor(fx, off); fy += __shfl_xor(fy, off); fz += __shfl_xor(fz, off);
  }
  if (lane == 0) {
    float* f = out + (size_t)((size_t)b*NL0 + l0)*3;
    f[0] = fx; f[1] = fy; f[2] = fz;
  }
}

extern "C" void kernel_launch(void* const* d_in, const int* in_sizes, int n_in,
                              void* d_out, int out_size, void* d_ws, size_t ws_size,
                              hipStream_t stream) {
  const float* x0   = (const float*)d_in[0];
  const float* x1   = (const float*)d_in[1];
  const float* pos0 = (const float*)d_in[2];
  const float* pos1 = (const float*)d_in[3];
  const void*  pad  = d_in[4];
  float* out = (float*)d_out;
  (void)in_sizes; (void)n_in; (void)out_size; (void)ws_size;

  float4*   srec   = (float4*)d_ws;                              // 128 KB
  uint32_t* cstart = (uint32_t*)((char*)d_ws + NB*NL1*16);       // 3.4 KB

  hipLaunchKernelGGL(prep_kernel, dim3(NB), dim3(256), 0, stream,
                     pos1, pad, srec, cstart);
  hipLaunchKernelGGL(fine_match_kernel, dim3(NB*NL0/QPB), dim3(TPB), 0, stream,
                     x0, x1, pos0, srec, cstart, out);
}

// Round 10
// 32.570 us; speedup vs baseline: 1.1535x; 1.1535x over previous
//
#include <hip/hip_runtime.h>
#include <stdint.h>

#define NB    4
#define NL0   2048
#define NL1   2048
#define NC    64
#define KMAX  128
#define CAP   192
#define NSLOT 3
#define NG1   9
#define NBINS 729
#define BINP  732          // 16B-aligned per-query bin pitch
#define FLOWN (NB*NL0*3)
#define QPB   8
#define TPB   512

__global__ __launch_bounds__(TPB, 8) void fine_match_kernel(
    const float* __restrict__ x0, const float* __restrict__ x1,
    const float* __restrict__ pos0, const float* __restrict__ pos1,
    const void* __restrict__ padraw, float* __restrict__ out)
{
  __shared__ float          s_x0[QPB*NC];       // 2 KB
  __shared__ unsigned short s_jj[QPB][CAP];     // 3 KB
  __shared__ float          s_corr[QPB][CAP];   // 6 KB, lane-private slots
  __shared__ float          s_bins[QPB][BINP];  // 22.9 KB, wave-private

  const int t = threadIdx.x;
  const int bid = blockIdx.x;
  const int b = bid >> 8;                 // 256 blocks per batch
  const int l0base = (bid & 255) * QPB;

  // ---- pad width detection: 4-byte (i32 / f32 bool) vs packed byte ----
  // (the ONLY block-wide barrier in the kernel)
  int wide;
  {
    const uint32_t* pi = (const uint32_t*)padraw;
    int ok4 = 1;
    for (int i = t; i < (NB*NL1)/4; i += TPB) {
      const uint32_t v = pi[i];
      ok4 &= (int)((v <= 1u) | (v == 0x3F800000u));
    }
    wide = __syncthreads_and(ok4);
  }

  const int wv = t >> 6, lane = t & 63;
  const int l0 = l0base + wv;

  // ---- wave-private init: zero own bins, stage own x0 row (no barriers) ----
  for (int i = lane; i < BINP; i += 64) s_bins[wv][i] = 0.0f;
  s_x0[wv*NC + lane] = x0[(size_t)(b*NL0 + l0)*NC + lane];

  const float* pq = pos0 + (size_t)(b*NL0 + l0)*3;   // wave-uniform broadcast loads
  const float p0x = pq[0], p0y = pq[1], p0z = pq[2];
  const float* pb = pos1 + (size_t)b*NL1*3;          // L2-resident (96 KB/batch)

  // ---- phase 1: radius scan from L2 + wave compaction (ordered by j) ----
  int cnt = 0;
  for (int base = 0; base < NL1; base += 64) {
    const int j = base + lane;
    const float dx = __fsub_rn(pb[j*3+0], p0x);
    const float dy = __fsub_rn(pb[j*3+1], p0y);
    const float dz = __fsub_rn(pb[j*3+2], p0z);
    const float d2 = __fadd_rn(__fadd_rn(__fmul_rn(dx,dx), __fmul_rn(dy,dy)), __fmul_rn(dz,dz));
    const bool ok = d2 < 0.0324f;              // strict <, matches reference
    const uint64_t m = __ballot(ok);
    if (ok) {
      const int pos = cnt + (int)__popcll(m & ((1ull << lane) - 1ull));
      if (pos < CAP) s_jj[wv][pos] = (unsigned short)j;
    }
    cnt += (int)__popcll(m);
  }
  if (cnt > CAP) cnt = CAP;
  // s_jj / s_corr / s_bins are wave-private: no barrier for the rest of the kernel

  // ---- phase 2: pad filter, rare exact rank-select, correlation ----
  const bool over = (cnt > KMAX);
  for (int s = 0; s < NSLOT; ++s) {
    if (64*s >= cnt) break;                    // wave-uniform early exit
    const int i = lane + 64*s;
    if (i < cnt) {
      float c = -1e30f;
      const int j = (int)s_jj[wv][i];
      bool k;
      if (wide) k = (((const uint32_t*)padraw)[b*NL1 + j] == 0u);   // i32 / f32(0,1.0) identical
      else      k = (((const uint8_t*)padraw)[b*NL1 + j] == 0);
      if (over && k) {  // rank over ALL in-radius candidates, tie-break by list order
        const float dx = __fsub_rn(pb[j*3+0], p0x);
        const float dy = __fsub_rn(pb[j*3+1], p0y);
        const float dz = __fsub_rn(pb[j*3+2], p0z);
        const float di = __fadd_rn(__fadd_rn(__fmul_rn(dx,dx), __fmul_rn(dy,dy)), __fmul_rn(dz,dz));
        int rank = 0;
        for (int m2 = 0; m2 < cnt; ++m2) {
          const int jm = (int)s_jj[wv][m2];
          const float ex = __fsub_rn(pb[jm*3+0], p0x);
          const float ey = __fsub_rn(pb[jm*3+1], p0y);
          const float ez = __fsub_rn(pb[jm*3+2], p0z);
          const float dm = __fadd_rn(__fadd_rn(__fmul_rn(ex,ex), __fmul_rn(ey,ey)), __fmul_rn(ez,ez));
          rank += (dm < di || (dm == di && m2 < i)) ? 1 : 0;
        }
        if (rank >= KMAX) k = false;
      }
      if (k) {
        const float* xr = x1 + ((size_t)b*NL1 + j)*NC;
        float acc = 0.0f;
        #pragma unroll
        for (int cc = 0; cc < NC; cc += 4) {
          const float4 v = *(const float4*)(xr + cc);
          const float4 q = *(const float4*)(&s_x0[wv*NC + cc]);  // LDS broadcast
          acc += q.x*v.x + q.y*v.y + q.z*v.z + q.w*v.w;
        }
        c = acc * 0.125f;   // / sqrt(64)
      }
      s_corr[wv][i] = c;
    }
  }

  // ---- phase 3: wave softmax stats (max, sum) ----
  float mx = -1e30f;
  for (int s = 0; s < NSLOT; ++s) {
    if (64*s >= cnt) break;
    const int i = lane + 64*s;
    if (i < cnt) { const float c = s_corr[wv][i]; if (c > mx) mx = c; }
  }
  for (int off = 32; off; off >>= 1) { const float o = __shfl_xor(mx, off); if (o > mx) mx = o; }
  float sum = 0.0f;
  for (int s = 0; s < NSLOT; ++s) {
    if (64*s >= cnt) break;
    const int i = lane + 64*s;
    if (i < cnt) { const float c = s_corr[wv][i]; if (c > -1e30f) sum += expf(c - mx); }
  }
  for (int off = 32; off; off >>= 1) sum += __shfl_xor(sum, off);
  const float inv = (sum > 0.0f) ? (1.0f / sum) : 0.0f;

  // ---- phase 4: flow + voxel scatter via LDS atomics (wave-private bins) ----
  float fx = 0.0f, fy = 0.0f, fz = 0.0f;
  for (int s = 0; s < NSLOT; ++s) {
    if (64*s >= cnt) break;
    const int i = lane + 64*s;
    if (i < cnt) {
      const float c = s_corr[wv][i];
      if (c > -1e30f) {
        const float pv = expf(c - mx) * inv;     // identical to phase-3 term * inv
        const int j = (int)s_jj[wv][i];
        const float dx = __fsub_rn(pb[j*3+0], p0x);
        const float dy = __fsub_rn(pb[j*3+1], p0y);
        const float dz = __fsub_rn(pb[j*3+2], p0z);
        fx += pv*dx; fy += pv*dy; fz += pv*dz;
        const float cx = __fdiv_rn(__fadd_rn(dx, 0.16f), 0.04f);
        const float cy = __fdiv_rn(__fadd_rn(dy, 0.16f), 0.04f);
        const float cz = __fdiv_rn(__fadd_rn(dz, 0.16f), 0.04f);
        int vx = (int)rintf(cx); vx = vx < 0 ? 0 : (vx > 8 ? 8 : vx);
        int vy = (int)rintf(cy); vy = vy < 0 ? 0 : (vy > 8 ? 8 : vy);
        int vz = (int)rintf(cz); vz = vz < 0 ? 0 : (vz > 8 ? 8 : vz);
        atomicAdd(&s_bins[wv][(vx*NG1 + vy)*NG1 + vz], pv);
      }
    }
  }
  for (int off = 32; off; off >>= 1) {
    fx += __shfl_xor(fx, off); fy += __shfl_xor(fy, off); fz += __shfl_xor(fz, off);
  }
  if (lane == 0) {
    float* f = out + (size_t)((size_t)b*NL0 + l0)*3;
    f[0] = fx; f[1] = fy; f[2] = fz;
  }

  // ---- phase 5: wave-private coalesced writeout (covers the zeros too) ----
  float* fd = out + FLOWN + (size_t)((size_t)b*NL0 + l0)*NBINS;
  for (int i = lane; i < NBINS; i += 64) fd[i] = s_bins[wv][i];
}

extern "C" void kernel_launch(void* const* d_in, const int* in_sizes, int n_in,
                              void* d_out, int out_size, void* d_ws, size_t ws_size,
                              hipStream_t stream) {
  const float* x0   = (const float*)d_in[0];
  const float* x1   = (const float*)d_in[1];
  const float* pos0 = (const float*)d_in[2];
  const float* pos1 = (const float*)d_in[3];
  const void*  pad  = d_in[4];
  float* out = (float*)d_out;
  (void)in_sizes; (void)n_in; (void)out_size; (void)d_ws; (void)ws_size;
  hipLaunchKernelGGL(fine_match_kernel, dim3(NB*NL0/QPB), dim3(TPB), 0, stream,
                     x0, x1, pos0, pos1, pad, out);
}